// Round 7
// baseline (79.353 us; speedup 1.0000x reference)
//
#include <hip/hip_runtime.h>

typedef __attribute__((ext_vector_type(8))) short short8;
typedef __attribute__((ext_vector_type(4))) float f32x4;

// ---------------- ws layout (bytes) ----------------
// rcp  : float [8][512]                        @ 0         (16384)
// wpre : bf16  [c=8][t=9][kb=8][co=512][8]     @ 16384     (4718592)
// xm   : bf16  [b=8][g=64][hp=34][col=34][8]   @ 4734976   (9469952)  (hp=0 / hp=33 are zero rows)
#define RCP_OFF   0
#define WPRE_OFF  16384
#define XM_OFF    4734976

__device__ __forceinline__ unsigned short f2bf(float f) {
  unsigned int u = __float_as_uint(f);
  u += 0x7FFFu + ((u >> 16) & 1u);       // round-to-nearest-even
  return (unsigned short)(u >> 16);
}

__device__ __forceinline__ void gload_lds16(const void* g, void* l) {
  __builtin_amdgcn_global_load_lds(
      (__attribute__((address_space(1))) void*)g,
      (__attribute__((address_space(3))) void*)l, 16, 0, 0);
}

// ---------------- fused prep: xm (blocks 0-511) | wpre (512-639) | xs (640-767) ----------------
__global__ __launch_bounds__(256) void prep_kernel(
    const float* __restrict__ x, const float* __restrict__ ys,
    const float* __restrict__ w,
    unsigned short* __restrict__ xm, unsigned short* __restrict__ wpre,
    float* __restrict__ rcp) {
  int bid = blockIdx.x;
  int tid = threadIdx.x;

  if (bid < 512) {
    // ---- xm: modulated x -> bf16, channel-grouped, padded h & w ----
    int half = bid & 1;
    int h = (bid >> 1) & 31;
    int b = bid >> 6;
    __shared__ float tile[256][33];
    int ci0 = half * 256;
#pragma unroll
    for (int r = 0; r < 32; ++r) {
      int ci = r * 8 + (tid >> 5);
      int wcol = tid & 31;
      float v = x[(((size_t)b * 512 + ci0 + ci) * 32 + h) * 32 + wcol];
      tile[ci][wcol] = v * ys[b * 512 + ci0 + ci];
    }
    __syncthreads();
    int g0 = half * 32;
    for (int r = 0; r < 5; ++r) {
      int idx = r * 256 + tid;                     // [gl(32)][col(34)]
      if (idx < 1088) {
        int gl = idx / 34;
        int col = idx - gl * 34;
        short8 v = {0,0,0,0,0,0,0,0};
        if (col != 0 && col != 33) {
          int wcol = col - 1;
#pragma unroll
          for (int j = 0; j < 8; ++j)
            v[j] = (short)f2bf(tile[gl * 8 + j][wcol]);
        }
        size_t off = ((((size_t)b * 64 + g0 + gl) * 34 + (h + 1)) * 34 + col) * 8;
        *reinterpret_cast<short8*>(xm + off) = v;
      }
    }
    if (h == 0 || h == 31) {
      int hp = (h == 0) ? 0 : 33;
      for (int r = 0; r < 5; ++r) {
        int idx = r * 256 + tid;
        if (idx < 1088) {
          int gl = idx / 34;
          int col = idx - gl * 34;
          short8 z = {0,0,0,0,0,0,0,0};
          size_t off = ((((size_t)b * 64 + g0 + gl) * 34 + hp) * 34 + col) * 8;
          *reinterpret_cast<short8*>(xm + off) = z;
        }
      }
    }
  } else if (bid < 640) {
    // ---- wpre: scaled weight -> bf16 fragment layout ----
    int pid = bid - 512;             // [c(8)][kb(8)][coh(2)]
    int coh = pid & 1;
    int kb = (pid >> 1) & 7;
    int c = pid >> 4;
    int co = coh * 256 + tid;
    int ci0 = c * 64 + kb * 8;
    const float* wp = w + (size_t)co * 4608 + (size_t)ci0 * 9;   // 72 contiguous floats
    float v[72];
    const f32x4* wp4 = reinterpret_cast<const f32x4*>(wp);
#pragma unroll
    for (int i = 0; i < 18; ++i) {
      f32x4 q = wp4[i];
      v[i * 4 + 0] = q[0]; v[i * 4 + 1] = q[1]; v[i * 4 + 2] = q[2]; v[i * 4 + 3] = q[3];
    }
    const float scale = 1.4731391274719738e-02f;   // (512*9)^-0.5
#pragma unroll
    for (int t = 0; t < 9; ++t) {
      short8 s;
#pragma unroll
      for (int j = 0; j < 8; ++j) s[j] = (short)f2bf(scale * v[j * 9 + t]);
      *reinterpret_cast<short8*>(wpre + ((((size_t)c * 9 + t) * 8 + kb) * 512 + co) * 8) = s;
    }
  } else {
    // ---- xs: demod rcp[b][o], one wave per o ----
    int pid = bid - 640;
    int wv = tid >> 6;
    int lane = tid & 63;
    int o = pid * 4 + wv;
    const float* wp = w + (size_t)o * 4608 + (size_t)lane * 72;  // 8 ci x 9 taps
    const float scale2 = 1.0f / 4608.0f;
    float w2[8];
#pragma unroll
    for (int j = 0; j < 8; ++j) {
      float s = 0.f;
#pragma unroll
      for (int k = 0; k < 9; ++k) { float vv = wp[j * 9 + k]; s += vv * vv; }
      w2[j] = s * scale2;
    }
#pragma unroll
    for (int b = 0; b < 8; ++b) {
      float p = 0.f;
#pragma unroll
      for (int j = 0; j < 8; ++j) {
        float y = ys[b * 512 + lane * 8 + j];
        p += y * y * w2[j];
      }
#pragma unroll
      for (int off = 32; off > 0; off >>= 1) p += __shfl_down(p, off);
      if (lane == 0) rcp[b * 512 + o] = 1.0f / sqrtf(p + 1e-8f);
    }
  }
}

// ---------------- main: implicit-GEMM direct conv, 4 independent blocks/CU ----------------
// grid 1024 = [sp(128)=b*16+hp][cog(8)], cog = XCD (bid&7) so each XCD's A slice
// (K x 64 Co = 0.59 MB) is L2-resident. Block 128 thr = 2 waves (wc = h-row).
// Tile 64 Co x 64 px (2 h-rows), FULL K per block (no K-split, no LDS reduction).
// Per wave per tap: 8 A global loads (reg dbuf, chunk-parity swapped refs),
// 4 ds_read_b128 B-frags (reg dbuf), 16 MFMA. 4 unsynchronized blocks per CU
// provide the latency hiding the previous 8-wave lockstep block lacked (m114).
// xbuf[2][kb=8][rr=4][col=34][16B] = 2 x 17408 B. One counted barrier per chunk.
__global__ __launch_bounds__(128, 2) void conv_main(
    const unsigned short* __restrict__ wpre,
    const unsigned short* __restrict__ xm,
    const float* __restrict__ rcp,
    const float* __restrict__ bias,
    float* __restrict__ out)
{
  __shared__ __align__(16) char smem[34816];

  int bid = blockIdx.x;
  int cog = bid & 7;                // = XCD (round-robin dispatch): 64 Co each
  int sp = bid >> 3;                // 0..127
  int b = sp >> 4;
  int hp = sp & 15;                 // h-pair: output rows 2hp, 2hp+1
  int tid = threadIdx.x;
  int lane = tid & 63;
  int wc = tid >> 6;                // wave id = h-row select
  int l15 = lane & 15, l4 = lane >> 4;

  f32x4 acc[4][2];
#pragma unroll
  for (int i = 0; i < 4; ++i)
#pragma unroll
    for (int jj = 0; jj < 2; ++jj) { f32x4 z = {0.f,0.f,0.f,0.f}; acc[i][jj] = z; }

  const unsigned short* xmb = xm + (size_t)b * (64 * 34 * 34 * 8);
  // A-frag base: element (kb = ks*4 + l4, co = cog*64 + mi*16 + l15)
  const unsigned short* wbase = wpre + ((size_t)l4 * 512 + cog * 64 + l15) * 8;
  // B-frag LDS base: addr = ((ks*4+l4)*4 + wc+kh)*544 + (nj*16+l15+kw)*16
  const int bbase = (l4 * 4 + wc) * 544 + l15 * 16;

  auto stageX = [&](int c, int buf) {
    char* xb = smem + buf * 17408;
#pragma unroll
    for (int i = 0; i < 8; ++i) {
      int idx = i * 128 + tid;               // [kb*4+rr (32)][col (34)] = 1088
      int kbr = idx / 34;
      int col = idx - kbr * 34;
      const unsigned short* src =
          xmb + (((size_t)(c * 8 + (kbr >> 2)) * 34 + 2 * hp + (kbr & 3)) * 34 + col) * 8;
      gload_lds16(src, xb + idx * 16);
    }
    if (tid < 64) {                          // wave-uniform extra (wave 0 only)
      int idx = 1024 + tid;
      int kbr = idx / 34;
      int col = idx - kbr * 34;
      const unsigned short* src =
          xmb + (((size_t)(c * 8 + (kbr >> 2)) * 34 + 2 * hp + (kbr & 3)) * 34 + col) * 8;
      gload_lds16(src, xb + idx * 16);
    }
  };

  auto loadA = [&](int ct, short8 (&a)[2][4]) {
    const unsigned short* p = wbase + (size_t)ct * 32768;
#pragma unroll
    for (int ks = 0; ks < 2; ++ks)
#pragma unroll
      for (int mi = 0; mi < 4; ++mi)
        a[ks][mi] = *reinterpret_cast<const short8*>(p + ks * 16384 + mi * 128);
  };

  auto loadB = [&](const char* xb, int t, short8 (&f)[2][2]) {
    int kh = t / 3, kw = t % 3;              // compile-time (t unrolled)
#pragma unroll
    for (int ks = 0; ks < 2; ++ks)
#pragma unroll
      for (int nj = 0; nj < 2; ++nj)
        f[ks][nj] = *reinterpret_cast<const short8*>(
            xb + bbase + ks * 8704 + kh * 544 + nj * 256 + kw * 16);
  };

  short8 A0[2][4], A1[2][4];

  // one chunk = 9 taps. Ae = even-t A buffer, Ao = odd-t. 9 odd -> roles swap
  // each chunk; caller alternates (A0,A1)/(A1,A0). All refs compile-time.
  auto chunk = [&](int c, short8 (&Ae)[2][4], short8 (&Ao)[2][4]) {
    const char* xb = smem + (c & 1) * 17408;
    if (c < 7) stageX(c + 1, (c + 1) & 1);   // async; drains at chunk-end barrier
    short8 Bp[2][2], Bq[2][2];
    loadB(xb, 0, Bp);
#pragma unroll
    for (int t = 0; t < 9; ++t) {
      int ct = c * 9 + t;
      short8 (&curA)[2][4] = (t & 1) ? Ao : Ae;
      short8 (&nxtA)[2][4] = (t & 1) ? Ae : Ao;
      short8 (&curB)[2][2] = (t & 1) ? Bq : Bp;
      short8 (&nxtB)[2][2] = (t & 1) ? Bp : Bq;
      if (ct < 71) loadA(ct + 1, nxtA);      // depth-1 A prefetch (global, L2)
      if (t < 8) loadB(xb, t + 1, nxtB);     // next-tap B prefetch (LDS)
#pragma unroll
      for (int ks = 0; ks < 2; ++ks)
#pragma unroll
        for (int nj = 0; nj < 2; ++nj)
#pragma unroll
          for (int mi = 0; mi < 4; ++mi)
            acc[mi][nj] = __builtin_amdgcn_mfma_f32_16x16x32_bf16(
                curA[ks][mi], curB[ks][nj], acc[mi][nj], 0, 0, 0);
    }
    if (c < 7) {
      // all but the 8 newest vmem ops (next-tap A prefetch) must be done ->
      // stageX(c+1) complete; lgkm(0): all ds_reads of this buffer retired.
      asm volatile("s_waitcnt vmcnt(8) lgkmcnt(0)" ::: "memory");
      __builtin_amdgcn_s_barrier();
      asm volatile("" ::: "memory");
    }
  };

  // prologue
  stageX(0, 0);
  loadA(0, A0);
  asm volatile("s_waitcnt vmcnt(8)" ::: "memory");   // stageX(0) done; loadA may fly
  __builtin_amdgcn_s_barrier();
  asm volatile("" ::: "memory");

  for (int cc = 0; cc < 8; cc += 2) {
    chunk(cc, A0, A1);
    chunk(cc + 1, A1, A0);
  }

  // ---- epilogue: demod + bias, fp32 NCHW store (no K-split reduction) ----
  const float* rcpb = rcp + b * 512;
  int h = 2 * hp + wc;
#pragma unroll
  for (int mi = 0; mi < 4; ++mi) {
    int ob = cog * 64 + mi * 16 + l4 * 4;
    float rc[4], bi[4];
#pragma unroll
    for (int jj = 0; jj < 4; ++jj) { rc[jj] = rcpb[ob + jj]; bi[jj] = bias[ob + jj]; }
#pragma unroll
    for (int nj = 0; nj < 2; ++nj) {
      int wcol = nj * 16 + l15;
#pragma unroll
      for (int jj = 0; jj < 4; ++jj)
        out[(((size_t)b * 512 + ob + jj) * 32 + h) * 32 + wcol] = acc[mi][nj][jj] * rc[jj] + bi[jj];
    }
  }
}

extern "C" void kernel_launch(void* const* d_in, const int* in_sizes, int n_in,
                              void* d_out, int out_size, void* d_ws, size_t ws_size,
                              hipStream_t stream) {
  const float* x    = (const float*)d_in[0];
  const float* ys   = (const float*)d_in[1];
  const float* w    = (const float*)d_in[2];
  const float* bias = (const float*)d_in[3];
  float* out = (float*)d_out;
  char* ws = (char*)d_ws;
  float* rcp = (float*)(ws + RCP_OFF);
  unsigned short* wpre = (unsigned short*)(ws + WPRE_OFF);
  unsigned short* xm   = (unsigned short*)(ws + XM_OFF);

  prep_kernel<<<768, 256, 0, stream>>>(x, ys, w, xm, wpre, rcp);
  conv_main<<<1024, 128, 0, stream>>>(wpre, xm, rcp, bias, out);
}